// Round 1
// baseline (456.827 us; speedup 1.0000x reference)
//
#include <hip/hip_runtime.h>

// Direct 3x3 conv, NCHW fp32. N=32, C_IN=3, H=W=224, C_OUT=64, stride 1, pad 1.
// One thread per output pixel, all 64 c_out per thread in 4 chunks of 16 accs.
// 27-float input window in VGPRs; weights via uniform (scalar-pipe) loads.

#define N_IMG 32
#define C_IN 3
#define H_ 224
#define W_ 224
#define C_OUT 64
#define NPIX (H_ * W_)      // 50176 = 196 * 256
#define COB 16              // c_out per chunk

__global__ __launch_bounds__(256) void conv3x3_kernel(
    const float* __restrict__ x,      // [N, C_IN, H, W]
    const float* __restrict__ wgt,    // [C_OUT, C_IN, 3, 3]
    const float* __restrict__ bias,   // [C_OUT]
    float* __restrict__ out)          // [N, C_OUT, H, W]
{
    const int p = blockIdx.x * 256 + threadIdx.x;   // pixel index within image
    const int n = blockIdx.y;
    const int h = p / W_;
    const int w = p - h * W_;

    // Load the 3x3x3 input window (zero padding at borders).
    float in_v[27];
    const float* xn = x + (size_t)n * C_IN * NPIX;
#pragma unroll
    for (int ci = 0; ci < 3; ++ci) {
#pragma unroll
        for (int dh = 0; dh < 3; ++dh) {
            const int hh = h + dh - 1;
            const bool hok = (unsigned)hh < (unsigned)H_;
#pragma unroll
            for (int dw = 0; dw < 3; ++dw) {
                const int ww = w + dw - 1;
                const bool ok = hok && ((unsigned)ww < (unsigned)W_);
                in_v[(ci * 3 + dh) * 3 + dw] =
                    ok ? xn[ci * NPIX + hh * W_ + ww] : 0.0f;
            }
        }
    }

    float* outp = out + (size_t)n * C_OUT * NPIX + p;
#pragma unroll
    for (int cb = 0; cb < C_OUT / COB; ++cb) {
        float acc[COB];
#pragma unroll
        for (int i = 0; i < COB; ++i) acc[i] = bias[cb * COB + i];
#pragma unroll
        for (int i = 0; i < COB; ++i) {
            const float* wp = wgt + (size_t)(cb * COB + i) * 27;
#pragma unroll
            for (int k = 0; k < 27; ++k) acc[i] += in_v[k] * wp[k];
        }
#pragma unroll
        for (int i = 0; i < COB; ++i)
            outp[(size_t)(cb * COB + i) * NPIX] = acc[i];
    }
}

extern "C" void kernel_launch(void* const* d_in, const int* in_sizes, int n_in,
                              void* d_out, int out_size, void* d_ws, size_t ws_size,
                              hipStream_t stream) {
    const float* x    = (const float*)d_in[0];
    const float* wgt  = (const float*)d_in[1];
    const float* bias = (const float*)d_in[2];
    float* out = (float*)d_out;

    dim3 grid(NPIX / 256, N_IMG);   // 196 x 32 blocks
    dim3 block(256);
    conv3x3_kernel<<<grid, block, 0, stream>>>(x, wgt, bias, out);
}